// Round 7
// baseline (767.812 us; speedup 1.0000x reference)
//
#include <hip/hip_runtime.h>
#include <hip/hip_bf16.h>

using short8 = __attribute__((ext_vector_type(8))) short;
using f32x4  = __attribute__((ext_vector_type(4))) float;

#define GLL16(g, l)                                                          \
  __builtin_amdgcn_global_load_lds(                                          \
      (const __attribute__((address_space(1))) void*)(g),                    \
      (__attribute__((address_space(3))) void*)(l), 16, 0, 0)

// ---------------------------------------------------------------------------
// Kernel 1: fused smooth-scale + block-128 fake quant, fp32 -> bf16
// ---------------------------------------------------------------------------
__global__ __launch_bounds__(256) void quant_kernel(
    const float* __restrict__ x, const float* __restrict__ smooth,
    __hip_bfloat16* __restrict__ xq, int D) {
  int tid = threadIdx.x;
  size_t qb = (size_t)blockIdx.x * 8 + (tid >> 5);
  int l = tid & 31;
  size_t base = qb * 128 + (size_t)l * 4;
  const float4 v = *(const float4*)(x + base);
  int d = (int)(base & (size_t)(D - 1));
  const float4 s = *(const float4*)(smooth + d);
  float y0 = v.x * s.x, y1 = v.y * s.y, y2 = v.z * s.z, y3 = v.w * s.w;
  float am = fmaxf(fmaxf(fabsf(y0), fabsf(y1)), fmaxf(fabsf(y2), fabsf(y3)));
#pragma unroll
  for (int off = 1; off < 32; off <<= 1)
    am = fmaxf(am, __shfl_xor(am, off, 64));
  float scale = fminf(fmaxf(am, 1e-12f) / 6.0f, 448.0f);
  float q0 = fminf(fmaxf(rintf(y0 / scale), -6.0f), 6.0f) * scale;
  float q1 = fminf(fmaxf(rintf(y1 / scale), -6.0f), 6.0f) * scale;
  float q2 = fminf(fmaxf(rintf(y2 / scale), -6.0f), 6.0f) * scale;
  float q3 = fminf(fmaxf(rintf(y3 / scale), -6.0f), 6.0f) * scale;
  union {
    __hip_bfloat16 h[4];
    uint2 u;
  } pk;
  pk.h[0] = __float2bfloat16(q0);
  pk.h[1] = __float2bfloat16(q1);
  pk.h[2] = __float2bfloat16(q2);
  pk.h[3] = __float2bfloat16(q3);
  *(uint2*)(xq + base) = pk.u;
}

// ---------------------------------------------------------------------------
// Kernel 2: W_eff = w_ternary + lora_b @ lora_a  (fp32 accum), cast to bf16.
// ---------------------------------------------------------------------------
__global__ __launch_bounds__(256) void wprep_kernel(
    const float* __restrict__ w, const float* __restrict__ la,
    const float* __restrict__ lb, __hip_bfloat16* __restrict__ weff, int Dk,
    int R) {
  __shared__ float lbs[16 * 64];
  int tid = threadIdx.x;
  int o0 = (blockIdx.x >> 4) * 16;
  int d = ((blockIdx.x & 15) << 8) + tid;
#pragma unroll
  for (int i = 0; i < 4; ++i) {
    int idx = tid + i * 256;
    lbs[idx] = lb[(size_t)(o0 + (idx >> 6)) * R + (idx & 63)];
  }
  __syncthreads();
  float acc[16];
#pragma unroll
  for (int oo = 0; oo < 16; ++oo) acc[oo] = 0.f;
  for (int r = 0; r < 64; ++r) {
    float av = la[(size_t)r * Dk + d];
#pragma unroll
    for (int oo = 0; oo < 16; ++oo) acc[oo] += lbs[oo * 64 + r] * av;
  }
#pragma unroll
  for (int oo = 0; oo < 16; ++oo) {
    size_t idx = (size_t)(o0 + oo) * Dk + d;
    weff[idx] = __float2bfloat16(w[idx] + acc[oo]);
  }
}

// ---------------------------------------------------------------------------
// Kernel 3: 256x256-tile 8-phase bf16 GEMM  (C = A * B^T + bias)
// ONE barrier per phase; reads issued ONE PHASE AHEAD of their MFMA (flow
// through the LDS pipe during the previous MFMA cluster); stages lag their
// region's last read by >=2 phases so a single barrier orders read-complete
// before restage; VMW(2) at P3/P7 retires the next-needed buffer (counted,
// never 0); compiler's auto counted-lgkmcnt gates each MFMA's operands.
// Hazard ledger (per-region): every stage follows its region's reads'
// completion by >=1 barrier in all waves; every cross-tile read follows
// VMW(2)+barrier covering its buffer; bF0's cross-tile read placed
// post-MFMA to avoid the register WAR.
// ---------------------------------------------------------------------------
#define BM 256
#define BN 256
#define BKT 64

__global__ __launch_bounds__(512, 2) void gemm_kernel(
    const __hip_bfloat16* __restrict__ A, const __hip_bfloat16* __restrict__ B,
    const float* __restrict__ bias, float* __restrict__ C, int M, int N,
    int K) {
  __shared__ __attribute__((aligned(16))) char lds[131072];

  const int tid = threadIdx.x;
  const int wave = tid >> 6, lane = tid & 63;
  const int wr = wave >> 2, wc = wave & 3;
  const int lr = lane & 15;
  const int hi16 = (lane >> 4) * 16;
  const int swx = (lr & 7) << 4;

  // XCD-aware bijective swizzle (nwg % 8 == 0: 1024 blocks)
  const int nwg = gridDim.x;
  const int cpx = nwg >> 3;
  const int swzb = (blockIdx.x & 7) * cpx + (blockIdx.x >> 3);
  const int ntn = N / BN;
  const int tm = swzb / ntn, tn = swzb % ntn;
  const size_t m0 = (size_t)tm * BM, n0 = (size_t)tn * BN;

  // staging: per-thread pre-swizzled global source; linear wave-uniform LDS dest
  const int trow = tid >> 3;
  const int csw = ((tid & 7) ^ (trow & 7)) * 8;
  const __hip_bfloat16* baseA = A + (m0 + trow) * (size_t)K + csw;
  const __hip_bfloat16* baseB = B + (n0 + trow) * (size_t)K + csw;
  char* sbase = lds + wave * 1024;

  // ds_read bases (per-lane, swizzled on read)
  const char* rdA = lds + (wr * 64 + lr) * 128;
  const char* rdB = lds + 32768 + (wc * 32 + lr) * 128;

#define STAGE(d, ab, h, kt)                                                   \
  do {                                                                        \
    const __hip_bfloat16* _g = ((ab) ? baseB : baseA) +                       \
                               (size_t)((h) * 128) * K + (size_t)(kt) * BKT;  \
    char* _l = sbase + (d) * 65536 + (ab) * 32768 + (h) * 16384;              \
    GLL16(_g, _l);                                                            \
    GLL16(_g + 64 * (size_t)K, _l + 8192);                                    \
  } while (0)

#define READ_A(DST, d, h)                                                     \
  _Pragma("unroll") for (int m = 0; m < 4; ++m)                               \
      _Pragma("unroll") for (int kk = 0; kk < 2; ++kk)                        \
          DST[m][kk] = *(const short8*)(rdA + (d) * 65536 + (h) * 16384 +     \
                                        m * 2048 + ((kk * 64 + hi16) ^ swx));

#define READ_B(DST, d, g)                                                     \
  _Pragma("unroll") for (int n = 0; n < 2; ++n)                               \
      _Pragma("unroll") for (int kk = 0; kk < 2; ++kk)                        \
          DST[n][kk] = *(const short8*)(rdB + (d) * 65536 + (g) * 16384 +     \
                                        n * 2048 + ((kk * 64 + hi16) ^ swx));

#define MFMA16(h, g, AF, BF)                                                  \
  _Pragma("unroll") for (int kk = 0; kk < 2; ++kk)                            \
      _Pragma("unroll") for (int m = 0; m < 4; ++m)                           \
          _Pragma("unroll") for (int n = 0; n < 2; ++n)                       \
              acc[h][m][g][n] = __builtin_amdgcn_mfma_f32_16x16x32_bf16(      \
                  AF[m][kk], BF[n][kk], acc[h][m][g][n], 0, 0, 0);

#define BAR __builtin_amdgcn_s_barrier()
#define SBAR0 __builtin_amdgcn_sched_barrier(0)
#define SETP1 __builtin_amdgcn_s_setprio(1)
#define SETP0 __builtin_amdgcn_s_setprio(0)
#define VMW(N)                                                                \
  asm volatile("s_waitcnt vmcnt(" #N ")" ::: "memory");                       \
  __builtin_amdgcn_sched_barrier(0)

  short8 aF0[4][2], aF1[4][2], bF0[2][2], bF1[2][2];
  f32x4 acc[2][4][2][2];
#pragma unroll
  for (int h = 0; h < 2; ++h)
#pragma unroll
    for (int m = 0; m < 4; ++m)
#pragma unroll
      for (int g = 0; g < 2; ++g)
#pragma unroll
        for (int n = 0; n < 2; ++n) acc[h][m][g][n] = (f32x4){0.f, 0.f, 0.f, 0.f};

  const int NK = K / BKT;  // 64

  // prologue: buf0 <- K0 (4 half-tiles); buf1 <- K1 {A-h0, B-g0}
  STAGE(0, 0, 0, 0);
  STAGE(0, 1, 0, 0);
  STAGE(0, 1, 1, 0);
  STAGE(0, 0, 1, 0);
  STAGE(1, 0, 0, 1);
  STAGE(1, 1, 0, 1);
  VMW(4);  // drain buf0 (own); barrier certifies all waves
  BAR;
  SBAR0;
  READ_A(aF0, 0, 0);  // P1 operands (steady-state P8 reads)
  READ_B(bF0, 0, 0);
  SBAR0;

  const int niter = NK / 2;  // 32
  for (int i = 0; i < niter; ++i) {
    const int k2 = (2 * i + 2 < NK) ? 2 * i + 2 : NK - 1;
    const int k3 = (2 * i + 3 < NK) ? 2 * i + 3 : NK - 1;
    // ---- K-tile 2i (buf0) ----
    // P1: (h0,g0)
    READ_B(bF1, 0, 1);           // P2 operand (buf0.Bg1: staged >=2 iters ago)
    STAGE(1, 1, 1, 2 * i + 1);   // b1.Bg1 <- K(2i+1)
    BAR;
    SBAR0;
    SETP1;
    MFMA16(0, 0, aF0, bF0);
    SETP0;
    // P2: (h0,g1)
    READ_A(aF1, 0, 1);           // P3 operand (buf0.Ah1)
    STAGE(1, 0, 1, 2 * i + 1);   // b1.Ah1 <- K(2i+1)
    BAR;
    SBAR0;
    SETP1;
    MFMA16(0, 1, aF0, bF1);
    SETP0;
    // P3: (h1,g1)
    STAGE(0, 0, 0, k2);          // b0.Ah0 <- K(2i+2)
    VMW(2);                      // retire buf1 K(2i+1) (leave P3's 2 loads)
    BAR;                         // all waves' VMW done -> buf1 readable
    SBAR0;
    SETP1;
    MFMA16(1, 1, aF1, bF1);
    SETP0;
    // P4: (h1,g0)
    READ_A(aF0, 1, 0);           // P5 operand (buf1.Ah0, covered by P3 VMW+BAR)
    STAGE(0, 1, 0, k2);          // b0.Bg0 <- K(2i+2)
    BAR;
    SBAR0;
    SETP1;
    MFMA16(1, 0, aF1, bF0);
    SETP0;
    READ_B(bF0, 1, 0);           // P5 operand (after bF0's last use; WAR-safe)
    SBAR0;
    // ---- K-tile 2i+1 (buf1) ----
    // P5: (h0,g0)
    READ_B(bF1, 1, 1);           // P6 operand (buf1.Bg1, covered by P3 VMW+BAR)
    STAGE(0, 1, 1, k2);          // b0.Bg1 <- K(2i+2)
    BAR;
    SBAR0;
    SETP1;
    MFMA16(0, 0, aF0, bF0);
    SETP0;
    // P6: (h0,g1)
    READ_A(aF1, 1, 1);           // P7 operand (buf1.Ah1)
    STAGE(0, 0, 1, k2);          // b0.Ah1 <- K(2i+2)
    BAR;
    SBAR0;
    SETP1;
    MFMA16(0, 1, aF0, bF1);
    SETP0;
    // P7: (h1,g1)
    STAGE(1, 0, 0, k3);          // b1.Ah0 <- K(2i+3)
    VMW(2);                      // retire buf0 K(2i+2) (leave P7's 2 loads)
    BAR;
    SBAR0;
    SETP1;
    MFMA16(1, 1, aF1, bF1);
    SETP0;
    // P8: (h1,g0)
    READ_A(aF0, 0, 0);           // next-P1 operand (buf0 K(2i+2); dead on last iter)
    STAGE(1, 1, 0, k3);          // b1.Bg0 <- K(2i+3)
    BAR;
    SBAR0;
    SETP1;
    MFMA16(1, 0, aF1, bF0);
    SETP0;
    READ_B(bF0, 0, 0);           // next-P1 operand
    SBAR0;
  }

  // epilogue: C/D layout col=lane&15, row=(lane>>4)*4+reg
#pragma unroll
  for (int h = 0; h < 2; ++h)
#pragma unroll
    for (int g = 0; g < 2; ++g)
#pragma unroll
      for (int n = 0; n < 2; ++n) {
        const int col = (int)n0 + g * 128 + wc * 32 + n * 16 + lr;
        const float bv = bias[col];
#pragma unroll
        for (int m = 0; m < 4; ++m) {
          const int row = (int)m0 + h * 128 + wr * 64 + m * 16 + (lane >> 4) * 4;
#pragma unroll
          for (int r = 0; r < 4; ++r)
            C[(size_t)(row + r) * N + col] = acc[h][m][g][n][r] + bv;
        }
      }
}

// ---------------------------------------------------------------------------
extern "C" void kernel_launch(void* const* d_in, const int* in_sizes, int n_in,
                              void* d_out, int out_size, void* d_ws,
                              size_t ws_size, hipStream_t stream) {
  const float* x = (const float*)d_in[0];
  const float* w = (const float*)d_in[1];
  const float* smooth = (const float*)d_in[2];
  const float* la = (const float*)d_in[3];
  const float* lb = (const float*)d_in[4];
  const float* bias = (const float*)d_in[5];
  float* out = (float*)d_out;

  const int K = in_sizes[2];      // 4096
  const int N = in_sizes[5];      // 4096
  const int M = in_sizes[0] / K;  // 16384
  const int R = in_sizes[3] / K;  // 64

  __hip_bfloat16* xq = (__hip_bfloat16*)d_ws;
  __hip_bfloat16* weff = xq + (size_t)M * K;

  {
    size_t qblocks = ((size_t)M * K) / 128;
    int blocks = (int)(qblocks / 8);
    quant_kernel<<<blocks, 256, 0, stream>>>(x, smooth, xq, K);
  }
  {
    int blocks = (N / 16) * (K / 256);
    wprep_kernel<<<blocks, 256, 0, stream>>>(w, la, lb, weff, K, R);
  }
  {
    int blocks = (M / BM) * (N / BN);
    gemm_kernel<<<blocks, 512, 0, stream>>>(xq, weff, bias, out, M, N, K);
  }
}